// Round 9
// baseline (260.953 us; speedup 1.0000x reference)
//
#include <hip/hip_runtime.h>
#include <math.h>

#define EMB   1024
#define S_LEN 1024
#define NQ    32
#define HEADS 16
#define FFN   4096
#define T_TOK 8192
#define EPS   1e-5f
#define MiB   (1024ull * 1024ull)

typedef unsigned short u16;
typedef __attribute__((ext_vector_type(8))) short short8;
typedef __attribute__((ext_vector_type(4))) float float4_t;

__device__ __forceinline__ u16 f2bf(float f) {
    unsigned u = __float_as_uint(f);
    u += 0x7FFF + ((u >> 16) & 1);   // round-to-nearest-even
    return (u16)(u >> 16);
}
__device__ __forceinline__ void async16(u16* lds, const u16* g) {
    __builtin_amdgcn_global_load_lds(
        (const __attribute__((address_space(1))) unsigned int*)g,
        (__attribute__((address_space(3))) unsigned int*)lds, 16, 0, 0);
}

#define N_W1 (FFN * NQ)            // 131072
#define N_W2 (EMB * FFN)           // 4194304
#define N_WC (EMB * NQ)            // 32768
#define NWBLK ((N_W1 + N_W2 + N_WC) / 256)   // 17024 exactly

// ---- K1: heterogeneous grid: blocks 0..511 = attention (qv inline from x),
//          blocks 512.. = weight f32->bf16 conversion.  No cross-block deps.
__global__ __launch_bounds__(256) void k_attn_prep(
        const float* __restrict__ x,  const float* __restrict__ tha,
        const float* __restrict__ w1, const float* __restrict__ w2,
        const float* __restrict__ wc,
        u16* __restrict__ w1b, u16* __restrict__ w2b, u16* __restrict__ wcb,
        u16* __restrict__ attnB) {
    __shared__ __align__(16) float2 kv[S_LEN];
    int bid = blockIdx.x;
    int tid = threadIdx.x;

    if (bid >= 512) {               // ---- weight conversion part ----
        int idx = (bid - 512) * 256 + tid;
        if (idx < N_W1)               w1b[idx] = f2bf(w1[idx]);
        else if (idx < N_W1 + N_W2)   w2b[idx - N_W1] = f2bf(w2[idx - N_W1]);
        else if (idx < N_W1 + N_W2 + N_WC) wcb[idx - N_W1 - N_W2] = f2bf(wc[idx - N_W1 - N_W2]);
        return;
    }

    // ---- attention part: bh = bid>>2, quarter = bid&3 ----
    int bh = bid >> 2;
    int b = bh >> 4, h = bh & 15;
    float c0 = __cosf(tha[2 * h]);
    float c1 = __cosf(tha[2 * h + 1]);
    for (int i = tid; i < S_LEN; i += 256) {
        float2 xv = *(const float2*)(x + (size_t)(b * S_LEN + i) * EMB + 2 * h);
        kv[i] = make_float2(c0 * __cosf(xv.x), c1 * __cosf(xv.y));
    }
    __syncthreads();
    int s = (bid & 3) * 256 + tid;
    float2 q = kv[s];
    float qx = q.x * 0.70710678f, qy = q.y * 0.70710678f;
    float den = 0.f, nx = 0.f, ny = 0.f;
    const float4* kv4 = (const float4*)kv;
#pragma unroll 2
    for (int m = 0; m < S_LEN / 2; ++m) {
        float4 k2 = kv4[m];
        float d0 = fmaf(qy, k2.y, qx * k2.x);
        float e0 = __expf(d0);            // |d| <= sqrt(2): no max-sub
        den += e0;
        nx = fmaf(e0, k2.x, nx);
        ny = fmaf(e0, k2.y, ny);
        float d1 = fmaf(qy, k2.w, qx * k2.z);
        float e1 = __expf(d1);
        den += e1;
        nx = fmaf(e1, k2.z, nx);
        ny = fmaf(e1, k2.w, ny);
    }
    float inv = 1.f / den;
    u16* o = attnB + (size_t)(b * S_LEN + s) * NQ + 2 * h;
    o[0] = f2bf(nx * inv);
    o[1] = f2bf(ny * inv);
}

// ---- K2: combine + LN1 + qf(LDS) + H = relu(qf @ w1^T)  (16 rows/block) ---
__global__ __launch_bounds__(256) void k_combine_ln_h(
        const u16* __restrict__ A,     // attnB [T,32] bf16
        const u16* __restrict__ B,     // wcb [EMB,32] bf16
        const float* __restrict__ X,   // x [T,EMB] f32
        const float* __restrict__ g1, const float* __restrict__ b1,
        const float* __restrict__ thf,
        const u16* __restrict__ W1,    // w1b [FFN,32] bf16
        float* __restrict__ x1,        // post-LN [T,EMB] f32
        u16* __restrict__ H) {         // [T,FFN] bf16
    __shared__ float red[4][16][2];
    __shared__ __align__(16) u16 qfl[16 * 32];
    __shared__ __align__(16) u16 hstage[4][16][68];   // 68 = 64 + 4 pad (banks)
    int tid = threadIdx.x, lane = tid & 63, wave = tid >> 6;
    int t0 = blockIdx.x * 16;
    int colbase = wave * 256;
    int rrow = (lane >> 4) * 4;
    short8 afr = *(const short8*)(A + (size_t)(t0 + (lane & 15)) * 32 + (lane >> 4) * 8);
    float4_t acc[16];
    float4_t zero = {0.f, 0.f, 0.f, 0.f};
#pragma unroll
    for (int tn = 0; tn < 16; ++tn) {
        short8 bfr = *(const short8*)(B + (size_t)(colbase + tn * 16 + (lane & 15)) * 32 + (lane >> 4) * 8);
        acc[tn] = __builtin_amdgcn_mfma_f32_16x16x32_bf16(afr, bfr, zero, 0, 0, 0);
    }
    float sm[4] = {0.f, 0.f, 0.f, 0.f}, sq[4] = {0.f, 0.f, 0.f, 0.f};
#pragma unroll
    for (int tn = 0; tn < 16; ++tn) {
        int nc = colbase + tn * 16 + (lane & 15);
#pragma unroll
        for (int r = 0; r < 4; ++r) {
            float v = acc[tn][r] + X[(size_t)(t0 + rrow + r) * EMB + nc];
            acc[tn][r] = v;
            sm[r] += v;
            sq[r] = fmaf(v, v, sq[r]);
        }
    }
#pragma unroll
    for (int o = 1; o < 16; o <<= 1) {
#pragma unroll
        for (int r = 0; r < 4; ++r) {
            sm[r] += __shfl_xor(sm[r], o, 64);
            sq[r] += __shfl_xor(sq[r], o, 64);
        }
    }
    if ((lane & 15) == 0) {
#pragma unroll
        for (int r = 0; r < 4; ++r) {
            red[wave][rrow + r][0] = sm[r];
            red[wave][rrow + r][1] = sq[r];
        }
    }
    __syncthreads();
    float mu[4], rs[4];
#pragma unroll
    for (int r = 0; r < 4; ++r) {
        float s = red[0][rrow + r][0] + red[1][rrow + r][0] +
                  red[2][rrow + r][0] + red[3][rrow + r][0];
        float q = red[0][rrow + r][1] + red[1][rrow + r][1] +
                  red[2][rrow + r][1] + red[3][rrow + r][1];
        float m = s * (1.f / EMB);
        mu[r] = m;
        rs[r] = rsqrtf(q * (1.f / EMB) - m * m + EPS);
    }
#pragma unroll
    for (int tn = 0; tn < 16; ++tn) {
        int nc = colbase + tn * 16 + (lane & 15);
        float g = g1[nc], bb = b1[nc];
#pragma unroll
        for (int r = 0; r < 4; ++r) {
            float y = (acc[tn][r] - mu[r]) * rs[r] * g + bb;
            x1[(size_t)(t0 + rrow + r) * EMB + nc] = y;
            if (nc < NQ)
                qfl[(rrow + r) * 32 + nc] = f2bf(__cosf(thf[nc]) * __cosf(y));
        }
    }
    __syncthreads();

    short8 afr2 = *(const short8*)&qfl[(lane & 15) * 32 + (lane >> 4) * 8];
    for (int g = 0; g < 16; ++g) {
#pragma unroll
        for (int t4 = 0; t4 < 4; ++t4) {
            int ncol = wave * 1024 + (g * 4 + t4) * 16;
            short8 bfr = *(const short8*)(W1 + (size_t)(ncol + (lane & 15)) * 32 + (lane >> 4) * 8);
            float4_t d = __builtin_amdgcn_mfma_f32_16x16x32_bf16(afr2, bfr, zero, 0, 0, 0);
#pragma unroll
            for (int r = 0; r < 4; ++r)
                hstage[wave][rrow + r][t4 * 16 + (lane & 15)] = f2bf(fmaxf(d[r], 0.f));
        }
        __syncthreads();
#pragma unroll
        for (int it = 0; it < 2; ++it) {
            int c = it * 64 + lane;          // chunk 0..127
            int row = c >> 3, cc = (c & 7) * 8;
            short8 v = *(const short8*)&hstage[wave][row][cc];
            *(short8*)(H + (size_t)(t0 + row) * FFN + wave * 1024 + g * 64 + cc) = v;
        }
        __syncthreads();
    }
}

// ---- K3: Y = H @ w2^T + X1 -- fat-wave-tile variant -----------------------
// BM=256 BN=128 BK=64, 4 waves (2m x 2n), per-wave tile 128x64 (was 64x64).
// LDS frag-read traffic per unit work: 96 -> 72 KB (-25%); staging fetch
// 64 -> 48 KB/unit (A staged once per 256-row panel).  Schedule identical to
// the verified ffn2_db: 2 barriers/tile, counted vmcnt, setprio, XOR swizzle
// (A tile [256][64] keeps 128-B rows -> same swizzle formulas).  Grid 256 =
// 1 block/CU, LDS 96 KiB dbuf.  Accumulation order per output unchanged ->
// bitwise-identical results.
__global__ __launch_bounds__(256, 1) void k_ffn2_fat(
        const u16* __restrict__ H, const u16* __restrict__ W2,
        const float* __restrict__ X1, float* __restrict__ Y) {
    __shared__ __align__(16) u16 smem[49152];   // A 2x16K + B 2x8K u16 = 96 KiB
    const int tid = threadIdx.x, lane = tid & 63, wave = tid >> 6;
    const int wm = wave >> 1, wn = wave & 1;    // 2 m-waves x 2 n-waves

    // XCD-chunked swizzle: nwg=256, %8==0 -> bijective. Each XCD: 4 m-panels x 8 n.
    int bid = blockIdx.x;
    int lid = (bid & 7) * 32 + (bid >> 3);
    const int m0 = (lid >> 3) * 256, n0 = (lid & 7) * 128;

    u16* A0 = smem;           u16* B0 = smem + 32768;
    u16* A1 = smem + 16384;   u16* B1 = smem + 40960;

    // staging: 128-B rows; 8 lanes/row; pre-swizzled source col (verified form)
    const int srow = tid >> 3;                          // 0..31
    const int scol = ((tid & 7) ^ (srow & 7)) << 3;     // u16 units
    // read-side swizzle (u16 units): same XOR as staging
    const int cb0 = ((0  + ((lane >> 4) * 16)) ^ ((lane & 7) << 4)) >> 1;  // kk=0
    const int cb1 = ((64 + ((lane >> 4) * 16)) ^ ((lane & 7) << 4)) >> 1;  // kk=1
    const int arow = lane & 15;

    auto stage = [&](u16* sA, u16* sB, int kt) {
#pragma unroll
        for (int j = 0; j < 8; ++j)     // A: 256 rows x 64 cols
            async16(sA + (j * 32 + wave * 8) * 64,
                    H + (size_t)(m0 + j * 32 + srow) * FFN + kt + scol);
#pragma unroll
        for (int j = 0; j < 4; ++j)     // B: 128 rows x 64 cols
            async16(sB + (j * 32 + wave * 8) * 64,
                    W2 + (size_t)(n0 + j * 32 + srow) * FFN + kt + scol);
    };

    float4_t acc[8][4];
    float4_t zero = {0.f, 0.f, 0.f, 0.f};
#pragma unroll
    for (int i = 0; i < 8; ++i)
#pragma unroll
        for (int j = 0; j < 4; ++j) acc[i][j] = zero;

    u16 *cA = A0, *cB = B0, *nA = A1, *nB = B1;
    stage(cA, cB, 0);                    // prologue: tile 0 in flight (12 ops)

#pragma unroll 1
    for (int t = 0; t < 64; ++t) {
        if (t + 1 < 64) {
            stage(nA, nB, (t + 1) * 64);                        // 12 vm ops
            asm volatile("s_waitcnt vmcnt(12)" ::: "memory");   // tile t landed
        } else {
            asm volatile("s_waitcnt vmcnt(0)" ::: "memory");
        }
        __builtin_amdgcn_s_barrier();    // current tile visible to all waves

        short8 af0[8], af1[8], bf0[4], bf1[4];
#pragma unroll
        for (int f = 0; f < 8; ++f) {
            af0[f] = *(const short8*)(cA + (wm * 128 + f * 16 + arow) * 64 + cb0);
            af1[f] = *(const short8*)(cA + (wm * 128 + f * 16 + arow) * 64 + cb1);
        }
#pragma unroll
        for (int f = 0; f < 4; ++f) {
            bf0[f] = *(const short8*)(cB + (wn * 64 + f * 16 + arow) * 64 + cb0);
            bf1[f] = *(const short8*)(cB + (wn * 64 + f * 16 + arow) * 64 + cb1);
        }
        __builtin_amdgcn_s_setprio(1);
#pragma unroll
        for (int i = 0; i < 8; ++i)
#pragma unroll
            for (int j = 0; j < 4; ++j)
                acc[i][j] = __builtin_amdgcn_mfma_f32_16x16x32_bf16(af0[i], bf0[j], acc[i][j], 0, 0, 0);
#pragma unroll
        for (int i = 0; i < 8; ++i)
#pragma unroll
            for (int j = 0; j < 4; ++j)
                acc[i][j] = __builtin_amdgcn_mfma_f32_16x16x32_bf16(af1[i], bf1[j], acc[i][j], 0, 0, 0);
        __builtin_amdgcn_s_setprio(0);
        __builtin_amdgcn_s_barrier();    // all reads of cA/cB done before reuse

        u16* tA = cA; cA = nA; nA = tA;
        u16* tB = cB; cB = nB; nB = tB;
    }

    // epilogue: C += X1, f32 out
#pragma unroll
    for (int i = 0; i < 8; ++i) {
        int mr = m0 + wm * 128 + i * 16 + (lane >> 4) * 4;
#pragma unroll
        for (int j = 0; j < 4; ++j) {
            int nc = n0 + wn * 64 + j * 16 + (lane & 15);
#pragma unroll
            for (int r = 0; r < 4; ++r) {
                size_t off = (size_t)(mr + r) * EMB + nc;
                Y[off] = acc[i][j][r] + X1[off];
            }
        }
    }
}

// ---- fallback-only kernels (small-ws path) --------------------------------
__global__ __launch_bounds__(256) void k_combine_ln(
        const u16* __restrict__ A, const u16* __restrict__ B,
        const float* __restrict__ X,
        const float* __restrict__ g1, const float* __restrict__ b1,
        const float* __restrict__ thf,
        float* __restrict__ x1, u16* __restrict__ qf) {
    __shared__ float red[4][16][2];
    int tid = threadIdx.x, lane = tid & 63, wave = tid >> 6;
    int t0 = blockIdx.x * 16;
    int colbase = wave * 256;
    int rrow = (lane >> 4) * 4;
    short8 afr = *(const short8*)(A + (size_t)(t0 + (lane & 15)) * 32 + (lane >> 4) * 8);
    float4_t acc[16];
    float4_t zero = {0.f, 0.f, 0.f, 0.f};
#pragma unroll
    for (int tn = 0; tn < 16; ++tn) {
        short8 bfr = *(const short8*)(B + (size_t)(colbase + tn * 16 + (lane & 15)) * 32 + (lane >> 4) * 8);
        acc[tn] = __builtin_amdgcn_mfma_f32_16x16x32_bf16(afr, bfr, zero, 0, 0, 0);
    }
    float sm[4] = {0.f, 0.f, 0.f, 0.f}, sq[4] = {0.f, 0.f, 0.f, 0.f};
#pragma unroll
    for (int tn = 0; tn < 16; ++tn) {
        int nc = colbase + tn * 16 + (lane & 15);
#pragma unroll
        for (int r = 0; r < 4; ++r) {
            float v = acc[tn][r] + X[(size_t)(t0 + rrow + r) * EMB + nc];
            acc[tn][r] = v;
            sm[r] += v;
            sq[r] = fmaf(v, v, sq[r]);
        }
    }
#pragma unroll
    for (int o = 1; o < 16; o <<= 1) {
#pragma unroll
        for (int r = 0; r < 4; ++r) {
            sm[r] += __shfl_xor(sm[r], o, 64);
            sq[r] += __shfl_xor(sq[r], o, 64);
        }
    }
    if ((lane & 15) == 0) {
#pragma unroll
        for (int r = 0; r < 4; ++r) {
            red[wave][rrow + r][0] = sm[r];
            red[wave][rrow + r][1] = sq[r];
        }
    }
    __syncthreads();
    float mu[4], rs[4];
#pragma unroll
    for (int r = 0; r < 4; ++r) {
        float s = red[0][rrow + r][0] + red[1][rrow + r][0] +
                  red[2][rrow + r][0] + red[3][rrow + r][0];
        float q = red[0][rrow + r][1] + red[1][rrow + r][1] +
                  red[2][rrow + r][1] + red[3][rrow + r][1];
        float m = s * (1.f / EMB);
        mu[r] = m;
        rs[r] = rsqrtf(q * (1.f / EMB) - m * m + EPS);
    }
#pragma unroll
    for (int tn = 0; tn < 16; ++tn) {
        int nc = colbase + tn * 16 + (lane & 15);
        float g = g1[nc], bb = b1[nc];
#pragma unroll
        for (int r = 0; r < 4; ++r) {
            float y = (acc[tn][r] - mu[r]) * rs[r] * g + bb;
            x1[(size_t)(t0 + rrow + r) * EMB + nc] = y;
            if (nc < NQ)
                qf[(size_t)(t0 + rrow + r) * NQ + nc] = f2bf(__cosf(thf[nc]) * __cosf(y));
        }
    }
}

__global__ __launch_bounds__(256) void k_ffn_fused(
        const u16* __restrict__ QF, const u16* __restrict__ W1,
        const u16* __restrict__ W2, const float* __restrict__ X1,
        float* __restrict__ Y) {
    const int K = FFN, N = EMB;
    __shared__ __align__(16) u16 sW[64 * 32];
    __shared__ __align__(16) u16 sA[128 * 64];
    __shared__ __align__(16) u16 sB[128 * 64];
    int tid = threadIdx.x, lane = tid & 63, wave = tid >> 6;
    int m0 = blockIdx.y * 128, n0 = blockIdx.x * 128;
    int wm = (wave >> 1) * 64, wn = (wave & 1) * 64;
    short8 aq[2];
#pragma unroll
    for (int tm2 = 0; tm2 < 2; ++tm2) {
        int m = m0 + wave * 32 + tm2 * 16 + (lane & 15);
        aq[tm2] = *(const short8*)(QF + (size_t)m * 32 + (lane >> 4) * 8);
    }
    const u16* gB = W2 + (size_t)(n0 + wave * 32 + (lane >> 3)) * K + (lane & 7) * 8;
    const u16* gW = W1 + (size_t)(wave * 16 + (lane >> 2)) * 32 + (lane & 3) * 8;
    float4_t acc[4][4];
    float4_t zero = {0.f, 0.f, 0.f, 0.f};
#pragma unroll
    for (int tm = 0; tm < 4; ++tm)
#pragma unroll
        for (int tn = 0; tn < 4; ++tn) acc[tm][tn] = zero;
    for (int kt = 0; kt < K; kt += 64) {
        async16(&sW[(size_t)(wave * 16) * 32], gW + (size_t)kt * 32);
#pragma unroll
        for (int i = 0; i < 4; ++i)
            async16(&sB[(size_t)(wave * 32 + i * 8) * 64], gB + (size_t)i * 8 * K + kt);
        __syncthreads();
        int r0 = (lane >> 4) * 4;
#pragma unroll
        for (int tm2 = 0; tm2 < 2; ++tm2) {
            int mrow = wave * 32 + tm2 * 16;
#pragma unroll
            for (int tf = 0; tf < 4; ++tf) {
                short8 bw = *(const short8*)&sW[(size_t)(tf * 16 + (lane & 15)) * 32 + (lane >> 4) * 8];
                float4_t d = __builtin_amdgcn_mfma_f32_16x16x32_bf16(aq[tm2], bw, zero, 0, 0, 0);
                int cc = tf * 16 + (lane & 15);
#pragma unroll
                for (int r = 0; r < 4; ++r)
                    sA[(size_t)(mrow + r0 + r) * 64 + cc] = f2bf(fmaxf(d[r], 0.f));
            }
        }
        __syncthreads();
#pragma unroll
        for (int kk = 0; kk < 2; ++kk) {
            short8 af[4], bfr[4];
#pragma unroll
            for (int tm = 0; tm < 4; ++tm)
                af[tm] = *(const short8*)&sA[(size_t)(wm + tm * 16 + (lane & 15)) * 64 + kk * 32 + (lane >> 4) * 8];
#pragma unroll
            for (int tn = 0; tn < 4; ++tn)
                bfr[tn] = *(const short8*)&sB[(size_t)(wn + tn * 16 + (lane & 15)) * 64 + kk * 32 + (lane >> 4) * 8];
#pragma unroll
            for (int tm = 0; tm < 4; ++tm)
#pragma unroll
                for (int tn = 0; tn < 4; ++tn)
                    acc[tm][tn] = __builtin_amdgcn_mfma_f32_16x16x32_bf16(af[tm], bfr[tn], acc[tm][tn], 0, 0, 0);
        }
        __syncthreads();
    }
#pragma unroll
    for (int tm = 0; tm < 4; ++tm) {
        int mr = m0 + wm + tm * 16 + (lane >> 4) * 4;
#pragma unroll
        for (int tn = 0; tn < 4; ++tn) {
            int nc = n0 + wn + tn * 16 + (lane & 15);
#pragma unroll
            for (int r = 0; r < 4; ++r) {
                size_t off = (size_t)(mr + r) * N + nc;
                Y[off] = acc[tm][tn][r] + X1[off];
            }
        }
    }
}

// ---- K4: in-place LN2 on f32 d_out ----------------------------------------
__global__ __launch_bounds__(256) void k_ln2(float* __restrict__ y,
                                             const float* __restrict__ g2,
                                             const float* __restrict__ b2) {
    __shared__ float red[8];
    int t = blockIdx.x;
    int tid = threadIdx.x, lane = tid & 63, wave = tid >> 6;
    int e0 = tid * 4;
    float* row = y + (size_t)t * EMB;
    float4 v4 = *(const float4*)(row + e0);
    float v[4] = {v4.x, v4.y, v4.z, v4.w};
    float sm = v[0] + v[1] + v[2] + v[3];
    float sq = v[0]*v[0] + v[1]*v[1] + v[2]*v[2] + v[3]*v[3];
    for (int o = 32; o > 0; o >>= 1) {
        sm += __shfl_xor(sm, o, 64);
        sq += __shfl_xor(sq, o, 64);
    }
    if (lane == 0) { red[wave * 2] = sm; red[wave * 2 + 1] = sq; }
    __syncthreads();
    sm = red[0] + red[2] + red[4] + red[6];
    sq = red[1] + red[3] + red[5] + red[7];
    float mu  = sm * (1.f / EMB);
    float var = sq * (1.f / EMB) - mu * mu;
    float rs  = rsqrtf(var + EPS);
    float4 o4;
    o4.x = (v[0] - mu) * rs * g2[e0 + 0] + b2[e0 + 0];
    o4.y = (v[1] - mu) * rs * g2[e0 + 1] + b2[e0 + 1];
    o4.z = (v[2] - mu) * rs * g2[e0 + 2] + b2[e0 + 2];
    o4.w = (v[3] - mu) * rs * g2[e0 + 3] + b2[e0 + 3];
    *(float4*)(row + e0) = o4;
}

extern "C" void kernel_launch(void* const* d_in, const int* in_sizes, int n_in,
                              void* d_out, int out_size, void* d_ws, size_t ws_size,
                              hipStream_t stream) {
    const float* x   = (const float*)d_in[0];
    const float* tha = (const float*)d_in[1];
    const float* thf = (const float*)d_in[2];
    const float* wc  = (const float*)d_in[3];
    const float* w1  = (const float*)d_in[4];
    const float* w2  = (const float*)d_in[5];
    const float* g1  = (const float*)d_in[6];
    const float* b1  = (const float*)d_in[7];
    const float* g2  = (const float*)d_in[8];
    const float* b2  = (const float*)d_in[9];
    float* out = (float*)d_out;

    char* ws = (char*)d_ws;
    float* x1    = (float*)(ws);                 //  0 .. 32 MiB
    u16*   attnB = (u16*)  (ws + 33 * MiB);      // 0.5 MiB
    u16*   qf    = (u16*)  (ws + 34 * MiB);      // 0.5 MiB (fallback only)
    u16*   w1b   = (u16*)  (ws + 35 * MiB);      // 0.25 MiB
    u16*   w2b   = (u16*)  (ws + 36 * MiB);      // 36 .. 44 MiB
    u16*   wcb   = (u16*)  (ws + 44 * MiB);      // 64 KiB
    u16*   hbuf  = (u16*)  (ws + 48 * MiB);      // 48 .. 112 MiB (split path)

    const bool split = ws_size >= (size_t)112 * MiB;

    k_attn_prep<<<512 + NWBLK, 256, 0, stream>>>(
        x, tha, w1, w2, wc, w1b, w2b, wcb, attnB);
    if (split) {
        k_combine_ln_h<<<T_TOK / 16, 256, 0, stream>>>(
            attnB, wcb, x, g1, b1, thf, w1b, x1, hbuf);
        k_ffn2_fat<<<dim3(256), 256, 0, stream>>>(hbuf, w2b, x1, out);
    } else {
        k_combine_ln<<<T_TOK / 16, 256, 0, stream>>>(
            attnB, wcb, x, g1, b1, thf, x1, qf);
        k_ffn_fused<<<dim3(EMB / 128, T_TOK / 128), 256, 0, stream>>>(
            qf, w1b, w2b, x1, out);
    }
    k_ln2<<<T_TOK, 256, 0, stream>>>(out, g2, b2);
}

// Round 10
// 249.041 us; speedup vs baseline: 1.0478x; 1.0478x over previous
//
#include <hip/hip_runtime.h>
#include <math.h>

#define EMB   1024
#define S_LEN 1024
#define NQ    32
#define HEADS 16
#define FFN   4096
#define T_TOK 8192
#define EPS   1e-5f
#define MiB   (1024ull * 1024ull)

typedef unsigned short u16;
typedef __attribute__((ext_vector_type(8))) short short8;
typedef __attribute__((ext_vector_type(4))) float float4_t;

__device__ __forceinline__ u16 f2bf(float f) {
    unsigned u = __float_as_uint(f);
    u += 0x7FFF + ((u >> 16) & 1);   // round-to-nearest-even
    return (u16)(u >> 16);
}
__device__ __forceinline__ void async16(u16* lds, const u16* g) {
    __builtin_amdgcn_global_load_lds(
        (const __attribute__((address_space(1))) unsigned int*)g,
        (__attribute__((address_space(3))) unsigned int*)lds, 16, 0, 0);
}

#define N_W1 (FFN * NQ)            // 131072
#define N_W2 (EMB * FFN)           // 4194304
#define N_WC (EMB * NQ)            // 32768
#define NWBLK ((N_W1 + N_W2 + N_WC) / 256)   // 17024 exactly

// ---- K1: heterogeneous grid: blocks 0..511 = attention (qv inline from x),
//          blocks 512.. = weight f32->bf16 conversion.  No cross-block deps.
__global__ __launch_bounds__(256) void k_attn_prep(
        const float* __restrict__ x,  const float* __restrict__ tha,
        const float* __restrict__ w1, const float* __restrict__ w2,
        const float* __restrict__ wc,
        u16* __restrict__ w1b, u16* __restrict__ w2b, u16* __restrict__ wcb,
        u16* __restrict__ attnB) {
    __shared__ __align__(16) float2 kv[S_LEN];
    int bid = blockIdx.x;
    int tid = threadIdx.x;

    if (bid >= 512) {               // ---- weight conversion part ----
        int idx = (bid - 512) * 256 + tid;
        if (idx < N_W1)               w1b[idx] = f2bf(w1[idx]);
        else if (idx < N_W1 + N_W2)   w2b[idx - N_W1] = f2bf(w2[idx - N_W1]);
        else if (idx < N_W1 + N_W2 + N_WC) wcb[idx - N_W1 - N_W2] = f2bf(wc[idx - N_W1 - N_W2]);
        return;
    }

    // ---- attention part: bh = bid>>2, quarter = bid&3 ----
    int bh = bid >> 2;
    int b = bh >> 4, h = bh & 15;
    float c0 = __cosf(tha[2 * h]);
    float c1 = __cosf(tha[2 * h + 1]);
    for (int i = tid; i < S_LEN; i += 256) {
        float2 xv = *(const float2*)(x + (size_t)(b * S_LEN + i) * EMB + 2 * h);
        kv[i] = make_float2(c0 * __cosf(xv.x), c1 * __cosf(xv.y));
    }
    __syncthreads();
    int s = (bid & 3) * 256 + tid;
    float2 q = kv[s];
    float qx = q.x * 0.70710678f, qy = q.y * 0.70710678f;
    float den = 0.f, nx = 0.f, ny = 0.f;
    const float4* kv4 = (const float4*)kv;
#pragma unroll 2
    for (int m = 0; m < S_LEN / 2; ++m) {
        float4 k2 = kv4[m];
        float d0 = fmaf(qy, k2.y, qx * k2.x);
        float e0 = __expf(d0);            // |d| <= sqrt(2): no max-sub
        den += e0;
        nx = fmaf(e0, k2.x, nx);
        ny = fmaf(e0, k2.y, ny);
        float d1 = fmaf(qy, k2.w, qx * k2.z);
        float e1 = __expf(d1);
        den += e1;
        nx = fmaf(e1, k2.z, nx);
        ny = fmaf(e1, k2.w, ny);
    }
    float inv = 1.f / den;
    u16* o = attnB + (size_t)(b * S_LEN + s) * NQ + 2 * h;
    o[0] = f2bf(nx * inv);
    o[1] = f2bf(ny * inv);
}

// ---- K2: combine + LN1 + qf(LDS) + H = relu(qf @ w1^T)  (16 rows/block) ---
__global__ __launch_bounds__(256) void k_combine_ln_h(
        const u16* __restrict__ A,     // attnB [T,32] bf16
        const u16* __restrict__ B,     // wcb [EMB,32] bf16
        const float* __restrict__ X,   // x [T,EMB] f32
        const float* __restrict__ g1, const float* __restrict__ b1,
        const float* __restrict__ thf,
        const u16* __restrict__ W1,    // w1b [FFN,32] bf16
        float* __restrict__ x1,        // post-LN [T,EMB] f32
        u16* __restrict__ H) {         // [T,FFN] bf16
    __shared__ float red[4][16][2];
    __shared__ __align__(16) u16 qfl[16 * 32];
    __shared__ __align__(16) u16 hstage[4][16][68];   // 68 = 64 + 4 pad (banks)
    int tid = threadIdx.x, lane = tid & 63, wave = tid >> 6;
    int t0 = blockIdx.x * 16;
    int colbase = wave * 256;
    int rrow = (lane >> 4) * 4;
    short8 afr = *(const short8*)(A + (size_t)(t0 + (lane & 15)) * 32 + (lane >> 4) * 8);
    float4_t acc[16];
    float4_t zero = {0.f, 0.f, 0.f, 0.f};
#pragma unroll
    for (int tn = 0; tn < 16; ++tn) {
        short8 bfr = *(const short8*)(B + (size_t)(colbase + tn * 16 + (lane & 15)) * 32 + (lane >> 4) * 8);
        acc[tn] = __builtin_amdgcn_mfma_f32_16x16x32_bf16(afr, bfr, zero, 0, 0, 0);
    }
    float sm[4] = {0.f, 0.f, 0.f, 0.f}, sq[4] = {0.f, 0.f, 0.f, 0.f};
#pragma unroll
    for (int tn = 0; tn < 16; ++tn) {
        int nc = colbase + tn * 16 + (lane & 15);
#pragma unroll
        for (int r = 0; r < 4; ++r) {
            float v = acc[tn][r] + X[(size_t)(t0 + rrow + r) * EMB + nc];
            acc[tn][r] = v;
            sm[r] += v;
            sq[r] = fmaf(v, v, sq[r]);
        }
    }
#pragma unroll
    for (int o = 1; o < 16; o <<= 1) {
#pragma unroll
        for (int r = 0; r < 4; ++r) {
            sm[r] += __shfl_xor(sm[r], o, 64);
            sq[r] += __shfl_xor(sq[r], o, 64);
        }
    }
    if ((lane & 15) == 0) {
#pragma unroll
        for (int r = 0; r < 4; ++r) {
            red[wave][rrow + r][0] = sm[r];
            red[wave][rrow + r][1] = sq[r];
        }
    }
    __syncthreads();
    float mu[4], rs[4];
#pragma unroll
    for (int r = 0; r < 4; ++r) {
        float s = red[0][rrow + r][0] + red[1][rrow + r][0] +
                  red[2][rrow + r][0] + red[3][rrow + r][0];
        float q = red[0][rrow + r][1] + red[1][rrow + r][1] +
                  red[2][rrow + r][1] + red[3][rrow + r][1];
        float m = s * (1.f / EMB);
        mu[r] = m;
        rs[r] = rsqrtf(q * (1.f / EMB) - m * m + EPS);
    }
#pragma unroll
    for (int tn = 0; tn < 16; ++tn) {
        int nc = colbase + tn * 16 + (lane & 15);
        float g = g1[nc], bb = b1[nc];
#pragma unroll
        for (int r = 0; r < 4; ++r) {
            float y = (acc[tn][r] - mu[r]) * rs[r] * g + bb;
            x1[(size_t)(t0 + rrow + r) * EMB + nc] = y;
            if (nc < NQ)
                qfl[(rrow + r) * 32 + nc] = f2bf(__cosf(thf[nc]) * __cosf(y));
        }
    }
    __syncthreads();

    short8 afr2 = *(const short8*)&qfl[(lane & 15) * 32 + (lane >> 4) * 8];
    for (int g = 0; g < 16; ++g) {
#pragma unroll
        for (int t4 = 0; t4 < 4; ++t4) {
            int ncol = wave * 1024 + (g * 4 + t4) * 16;
            short8 bfr = *(const short8*)(W1 + (size_t)(ncol + (lane & 15)) * 32 + (lane >> 4) * 8);
            float4_t d = __builtin_amdgcn_mfma_f32_16x16x32_bf16(afr2, bfr, zero, 0, 0, 0);
#pragma unroll
            for (int r = 0; r < 4; ++r)
                hstage[wave][rrow + r][t4 * 16 + (lane & 15)] = f2bf(fmaxf(d[r], 0.f));
        }
        __syncthreads();
#pragma unroll
        for (int it = 0; it < 2; ++it) {
            int c = it * 64 + lane;          // chunk 0..127
            int row = c >> 3, cc = (c & 7) * 8;
            short8 v = *(const short8*)&hstage[wave][row][cc];
            *(short8*)(H + (size_t)(t0 + row) * FFN + wave * 1024 + g * 64 + cc) = v;
        }
        __syncthreads();
    }
}

// ---- K3: Y = H @ w2^T + X1 -- verified ffn2_db (64 us, MfmaUtil 44%) ------
// 128x128 tile, 4 waves 64x64 each, 64-KiB LDS dbuf -> 2 blocks/CU.  The
// 2-blk/CU cross-block overlap (m114) is load-bearing: both 1-blk/CU
// variants measured worse (R2: 87 us, R9: 99 us).  Do not trade it away.
__global__ __launch_bounds__(256, 2) void k_ffn2_db(
        const u16* __restrict__ H, const u16* __restrict__ W2,
        const float* __restrict__ X1, float* __restrict__ Y) {
    __shared__ __align__(16) u16 smem[32768];
    const int tid = threadIdx.x, lane = tid & 63, wave = tid >> 6;
    const int wm = wave >> 1, wn = wave & 1;
    int bid = blockIdx.x;
    int lid = (bid & 7) * 64 + (bid >> 3);
    const int m0 = (lid >> 3) * 128, n0 = (lid & 7) * 128;
    u16* A0 = smem;          u16* B0 = smem + 8192;
    u16* A1 = smem + 16384;  u16* B1 = smem + 24576;
    const int srow = tid >> 3;
    const int scol = ((tid & 7) ^ (srow & 7)) << 3;
    const int cb0 = ((0  + ((lane >> 4) * 16)) ^ ((lane & 7) << 4)) >> 1;
    const int cb1 = ((64 + ((lane >> 4) * 16)) ^ ((lane & 7) << 4)) >> 1;
    const int arow = lane & 15;
    auto stage = [&](u16* sA, u16* sB, int kt) {
#pragma unroll
        for (int j = 0; j < 4; ++j)
            async16(sA + (j * 32 + wave * 8) * 64,
                    H + (size_t)(m0 + j * 32 + srow) * FFN + kt + scol);
#pragma unroll
        for (int j = 0; j < 4; ++j)
            async16(sB + (j * 32 + wave * 8) * 64,
                    W2 + (size_t)(n0 + j * 32 + srow) * FFN + kt + scol);
    };
    float4_t acc[4][4];
    float4_t zero = {0.f, 0.f, 0.f, 0.f};
#pragma unroll
    for (int i = 0; i < 4; ++i)
#pragma unroll
        for (int j = 0; j < 4; ++j) acc[i][j] = zero;
    u16 *cA = A0, *cB = B0, *nA = A1, *nB = B1;
    stage(cA, cB, 0);
#pragma unroll 1
    for (int t = 0; t < 64; ++t) {
        if (t + 1 < 64) {
            stage(nA, nB, (t + 1) * 64);
            asm volatile("s_waitcnt vmcnt(8)" ::: "memory");
        } else {
            asm volatile("s_waitcnt vmcnt(0)" ::: "memory");
        }
        __builtin_amdgcn_s_barrier();
        short8 af0[4], af1[4], bf0[4], bf1[4];
#pragma unroll
        for (int f = 0; f < 4; ++f) {
            af0[f] = *(const short8*)(cA + (wm * 64 + f * 16 + arow) * 64 + cb0);
            af1[f] = *(const short8*)(cA + (wm * 64 + f * 16 + arow) * 64 + cb1);
        }
#pragma unroll
        for (int f = 0; f < 4; ++f) {
            bf0[f] = *(const short8*)(cB + (wn * 64 + f * 16 + arow) * 64 + cb0);
            bf1[f] = *(const short8*)(cB + (wn * 64 + f * 16 + arow) * 64 + cb1);
        }
        __builtin_amdgcn_s_setprio(1);
#pragma unroll
        for (int i = 0; i < 4; ++i)
#pragma unroll
            for (int j = 0; j < 4; ++j)
                acc[i][j] = __builtin_amdgcn_mfma_f32_16x16x32_bf16(af0[i], bf0[j], acc[i][j], 0, 0, 0);
#pragma unroll
        for (int i = 0; i < 4; ++i)
#pragma unroll
            for (int j = 0; j < 4; ++j)
                acc[i][j] = __builtin_amdgcn_mfma_f32_16x16x32_bf16(af1[i], bf1[j], acc[i][j], 0, 0, 0);
        __builtin_amdgcn_s_setprio(0);
        __builtin_amdgcn_s_barrier();
        u16* tA = cA; cA = nA; nA = tA;
        u16* tB = cB; cB = nB; nB = tB;
    }
#pragma unroll
    for (int i = 0; i < 4; ++i) {
        int mr = m0 + wm * 64 + i * 16 + (lane >> 4) * 4;
#pragma unroll
        for (int j = 0; j < 4; ++j) {
            int nc = n0 + wn * 64 + j * 16 + (lane & 15);
#pragma unroll
            for (int r = 0; r < 4; ++r) {
                size_t off = (size_t)(mr + r) * EMB + nc;
                Y[off] = acc[i][j][r] + X1[off];
            }
        }
    }
}

// ---- fallback-only kernels (small-ws path) --------------------------------
__global__ __launch_bounds__(256) void k_combine_ln(
        const u16* __restrict__ A, const u16* __restrict__ B,
        const float* __restrict__ X,
        const float* __restrict__ g1, const float* __restrict__ b1,
        const float* __restrict__ thf,
        float* __restrict__ x1, u16* __restrict__ qf) {
    __shared__ float red[4][16][2];
    int tid = threadIdx.x, lane = tid & 63, wave = tid >> 6;
    int t0 = blockIdx.x * 16;
    int colbase = wave * 256;
    int rrow = (lane >> 4) * 4;
    short8 afr = *(const short8*)(A + (size_t)(t0 + (lane & 15)) * 32 + (lane >> 4) * 8);
    float4_t acc[16];
    float4_t zero = {0.f, 0.f, 0.f, 0.f};
#pragma unroll
    for (int tn = 0; tn < 16; ++tn) {
        short8 bfr = *(const short8*)(B + (size_t)(colbase + tn * 16 + (lane & 15)) * 32 + (lane >> 4) * 8);
        acc[tn] = __builtin_amdgcn_mfma_f32_16x16x32_bf16(afr, bfr, zero, 0, 0, 0);
    }
    float sm[4] = {0.f, 0.f, 0.f, 0.f}, sq[4] = {0.f, 0.f, 0.f, 0.f};
#pragma unroll
    for (int tn = 0; tn < 16; ++tn) {
        int nc = colbase + tn * 16 + (lane & 15);
#pragma unroll
        for (int r = 0; r < 4; ++r) {
            float v = acc[tn][r] + X[(size_t)(t0 + rrow + r) * EMB + nc];
            acc[tn][r] = v;
            sm[r] += v;
            sq[r] = fmaf(v, v, sq[r]);
        }
    }
#pragma unroll
    for (int o = 1; o < 16; o <<= 1) {
#pragma unroll
        for (int r = 0; r < 4; ++r) {
            sm[r] += __shfl_xor(sm[r], o, 64);
            sq[r] += __shfl_xor(sq[r], o, 64);
        }
    }
    if ((lane & 15) == 0) {
#pragma unroll
        for (int r = 0; r < 4; ++r) {
            red[wave][rrow + r][0] = sm[r];
            red[wave][rrow + r][1] = sq[r];
        }
    }
    __syncthreads();
    float mu[4], rs[4];
#pragma unroll
    for (int r = 0; r < 4; ++r) {
        float s = red[0][rrow + r][0] + red[1][rrow + r][0] +
                  red[2][rrow + r][0] + red[3][rrow + r][0];
        float q = red[0][rrow + r][1] + red[1][rrow + r][1] +
                  red[2][rrow + r][1] + red[3][rrow + r][1];
        float m = s * (1.f / EMB);
        mu[r] = m;
        rs[r] = rsqrtf(q * (1.f / EMB) - m * m + EPS);
    }
#pragma unroll
    for (int tn = 0; tn < 16; ++tn) {
        int nc = colbase + tn * 16 + (lane & 15);
        float g = g1[nc], bb = b1[nc];
#pragma unroll
        for (int r = 0; r < 4; ++r) {
            float y = (acc[tn][r] - mu[r]) * rs[r] * g + bb;
            x1[(size_t)(t0 + rrow + r) * EMB + nc] = y;
            if (nc < NQ)
                qf[(size_t)(t0 + rrow + r) * NQ + nc] = f2bf(__cosf(thf[nc]) * __cosf(y));
        }
    }
}

__global__ __launch_bounds__(256) void k_ffn_fused(
        const u16* __restrict__ QF, const u16* __restrict__ W1,
        const u16* __restrict__ W2, const float* __restrict__ X1,
        float* __restrict__ Y) {
    const int K = FFN, N = EMB;
    __shared__ __align__(16) u16 sW[64 * 32];
    __shared__ __align__(16) u16 sA[128 * 64];
    __shared__ __align__(16) u16 sB[128 * 64];
    int tid = threadIdx.x, lane = tid & 63, wave = tid >> 6;
    int m0 = blockIdx.y * 128, n0 = blockIdx.x * 128;
    int wm = (wave >> 1) * 64, wn = (wave & 1) * 64;
    short8 aq[2];
#pragma unroll
    for (int tm2 = 0; tm2 < 2; ++tm2) {
        int m = m0 + wave * 32 + tm2 * 16 + (lane & 15);
        aq[tm2] = *(const short8*)(QF + (size_t)m * 32 + (lane >> 4) * 8);
    }
    const u16* gB = W2 + (size_t)(n0 + wave * 32 + (lane >> 3)) * K + (lane & 7) * 8;
    const u16* gW = W1 + (size_t)(wave * 16 + (lane >> 2)) * 32 + (lane & 3) * 8;
    float4_t acc[4][4];
    float4_t zero = {0.f, 0.f, 0.f, 0.f};
#pragma unroll
    for (int tm = 0; tm < 4; ++tm)
#pragma unroll
        for (int tn = 0; tn < 4; ++tn) acc[tm][tn] = zero;
    for (int kt = 0; kt < K; kt += 64) {
        async16(&sW[(size_t)(wave * 16) * 32], gW + (size_t)kt * 32);
#pragma unroll
        for (int i = 0; i < 4; ++i)
            async16(&sB[(size_t)(wave * 32 + i * 8) * 64], gB + (size_t)i * 8 * K + kt);
        __syncthreads();
        int r0 = (lane >> 4) * 4;
#pragma unroll
        for (int tm2 = 0; tm2 < 2; ++tm2) {
            int mrow = wave * 32 + tm2 * 16;
#pragma unroll
            for (int tf = 0; tf < 4; ++tf) {
                short8 bw = *(const short8*)&sW[(size_t)(tf * 16 + (lane & 15)) * 32 + (lane >> 4) * 8];
                float4_t d = __builtin_amdgcn_mfma_f32_16x16x32_bf16(aq[tm2], bw, zero, 0, 0, 0);
                int cc = tf * 16 + (lane & 15);
#pragma unroll
                for (int r = 0; r < 4; ++r)
                    sA[(size_t)(mrow + r0 + r) * 64 + cc] = f2bf(fmaxf(d[r], 0.f));
            }
        }
        __syncthreads();
#pragma unroll
        for (int kk = 0; kk < 2; ++kk) {
            short8 af[4], bfr[4];
#pragma unroll
            for (int tm = 0; tm < 4; ++tm)
                af[tm] = *(const short8*)&sA[(size_t)(wm + tm * 16 + (lane & 15)) * 64 + kk * 32 + (lane >> 4) * 8];
#pragma unroll
            for (int tn = 0; tn < 4; ++tn)
                bfr[tn] = *(const short8*)&sB[(size_t)(wn + tn * 16 + (lane & 15)) * 64 + kk * 32 + (lane >> 4) * 8];
#pragma unroll
            for (int tm = 0; tm < 4; ++tm)
#pragma unroll
                for (int tn = 0; tn < 4; ++tn)
                    acc[tm][tn] = __builtin_amdgcn_mfma_f32_16x16x32_bf16(af[tm], bfr[tn], acc[tm][tn], 0, 0, 0);
        }
        __syncthreads();
    }
#pragma unroll
    for (int tm = 0; tm < 4; ++tm) {
        int mr = m0 + wm + tm * 16 + (lane >> 4) * 4;
#pragma unroll
        for (int tn = 0; tn < 4; ++tn) {
            int nc = n0 + wn + tn * 16 + (lane & 15);
#pragma unroll
            for (int r = 0; r < 4; ++r) {
                size_t off = (size_t)(mr + r) * N + nc;
                Y[off] = acc[tm][tn][r] + X1[off];
            }
        }
    }
}

// ---- K4: in-place LN2 on f32 d_out ----------------------------------------
__global__ __launch_bounds__(256) void k_ln2(float* __restrict__ y,
                                             const float* __restrict__ g2,
                                             const float* __restrict__ b2) {
    __shared__ float red[8];
    int t = blockIdx.x;
    int tid = threadIdx.x, lane = tid & 63, wave = tid >> 6;
    int e0 = tid * 4;
    float* row = y + (size_t)t * EMB;
    float4 v4 = *(const float4*)(row + e0);
    float v[4] = {v4.x, v4.y, v4.z, v4.w};
    float sm = v[0] + v[1] + v[2] + v[3];
    float sq = v[0]*v[0] + v[1]*v[1] + v[2]*v[2] + v[3]*v[3];
    for (int o = 32; o > 0; o >>= 1) {
        sm += __shfl_xor(sm, o, 64);
        sq += __shfl_xor(sq, o, 64);
    }
    if (lane == 0) { red[wave * 2] = sm; red[wave * 2 + 1] = sq; }
    __syncthreads();
    sm = red[0] + red[2] + red[4] + red[6];
    sq = red[1] + red[3] + red[5] + red[7];
    float mu  = sm * (1.f / EMB);
    float var = sq * (1.f / EMB) - mu * mu;
    float rs  = rsqrtf(var + EPS);
    float4 o4;
    o4.x = (v[0] - mu) * rs * g2[e0 + 0] + b2[e0 + 0];
    o4.y = (v[1] - mu) * rs * g2[e0 + 1] + b2[e0 + 1];
    o4.z = (v[2] - mu) * rs * g2[e0 + 2] + b2[e0 + 2];
    o4.w = (v[3] - mu) * rs * g2[e0 + 3] + b2[e0 + 3];
    *(float4*)(row + e0) = o4;
}

extern "C" void kernel_launch(void* const* d_in, const int* in_sizes, int n_in,
                              void* d_out, int out_size, void* d_ws, size_t ws_size,
                              hipStream_t stream) {
    const float* x   = (const float*)d_in[0];
    const float* tha = (const float*)d_in[1];
    const float* thf = (const float*)d_in[2];
    const float* wc  = (const float*)d_in[3];
    const float* w1  = (const float*)d_in[4];
    const float* w2  = (const float*)d_in[5];
    const float* g1  = (const float*)d_in[6];
    const float* b1  = (const float*)d_in[7];
    const float* g2  = (const float*)d_in[8];
    const float* b2  = (const float*)d_in[9];
    float* out = (float*)d_out;

    char* ws = (char*)d_ws;
    float* x1    = (float*)(ws);                 //  0 .. 32 MiB
    u16*   attnB = (u16*)  (ws + 33 * MiB);      // 0.5 MiB
    u16*   qf    = (u16*)  (ws + 34 * MiB);      // 0.5 MiB (fallback only)
    u16*   w1b   = (u16*)  (ws + 35 * MiB);      // 0.25 MiB
    u16*   w2b   = (u16*)  (ws + 36 * MiB);      // 36 .. 44 MiB
    u16*   wcb   = (u16*)  (ws + 44 * MiB);      // 64 KiB
    u16*   hbuf  = (u16*)  (ws + 48 * MiB);      // 48 .. 112 MiB (split path)

    const bool split = ws_size >= (size_t)112 * MiB;

    k_attn_prep<<<512 + NWBLK, 256, 0, stream>>>(
        x, tha, w1, w2, wc, w1b, w2b, wcb, attnB);
    if (split) {
        k_combine_ln_h<<<T_TOK / 16, 256, 0, stream>>>(
            attnB, wcb, x, g1, b1, thf, w1b, x1, hbuf);
        k_ffn2_db<<<dim3(512), 256, 0, stream>>>(hbuf, w2b, x1, out);
    } else {
        k_combine_ln<<<T_TOK / 16, 256, 0, stream>>>(
            attnB, wcb, x, g1, b1, thf, x1, qf);
        k_ffn_fused<<<dim3(EMB / 128, T_TOK / 128), 256, 0, stream>>>(
            qf, w1b, w2b, x1, out);
    }
    k_ln2<<<T_TOK, 256, 0, stream>>>(out, g2, b2);
}